// Round 1
// baseline (773.887 us; speedup 1.0000x reference)
//
#include <hip/hip_runtime.h>
#include <hip/hip_bf16.h>

typedef __attribute__((ext_vector_type(8))) unsigned short u16x8;
typedef __attribute__((ext_vector_type(4))) unsigned short u16x4;
typedef __attribute__((ext_vector_type(8))) __bf16 bf16x8;
typedef __attribute__((ext_vector_type(4))) float f32x4;

__device__ __forceinline__ unsigned short f2bf(float f) {
  unsigned u = __float_as_uint(f);
  return (unsigned short)((u + 0x7fffu + ((u >> 16) & 1u)) >> 16);  // RNE
}

// swizzled byte offset into a [16 edges][<=128 feats] bf16 buffer, row stride 256B.
// 16B chunks within a row are XOR-permuted by (edge&7) to avoid bank conflicts.
__device__ __forceinline__ int swz(int edge, int feat) {
  return edge * 256 + (((feat >> 3) ^ (edge & 7)) << 4) + (feat & 7) * 2;
}

// ---------------- prep: transpose weights to bf16 [n][k] ----------------
__global__ void prep_weights(const float* __restrict__ W1, const float* __restrict__ W2,
                             const float* __restrict__ W3, const float* __restrict__ W4,
                             unsigned short* __restrict__ wt) {
  int i = blockIdx.x * 256 + threadIdx.x;
  if (i >= 22528) return;
  float v;
  if (i < 4096)       { int n = i >> 6, k = i & 63;                 v = W1[k * 64 + n]; }
  else if (i < 12288) { int j = i - 4096;  int n = j >> 6, k = j & 63;   v = W2[k * 128 + n]; }
  else if (i < 20480) { int j = i - 12288; int n = j >> 7, k = j & 127;  v = W3[k * 64 + n]; }
  else                { int j = i - 20480; int n = j >> 6, k = j & 63;   v = W4[k * 32 + n]; }
  wt[i] = f2bf(v);
}

// ---------------- one MLP layer: dst = relu(W^T srcH + b), all per-wave ----------------
template <int MT, int KS>
__device__ __forceinline__ void mlp_layer(const unsigned char* src, unsigned char* dst,
                                          const u16x8 (&wf)[MT][KS],
                                          const float* __restrict__ biasL, int lane) {
  const int edge = lane & 15, g = lane >> 4;
  asm volatile("s_waitcnt lgkmcnt(0)" ::: "memory");   // prior LDS writes visible wave-wide
  u16x8 bfrag[KS];
#pragma unroll
  for (int ks = 0; ks < KS; ++ks)
    bfrag[ks] = *(const u16x8*)(src + swz(edge, ks * 32 + g * 8));
#pragma unroll
  for (int mt = 0; mt < MT; ++mt) {
    const float4 bv = *(const float4*)(biasL + mt * 16 + g * 4);
    f32x4 acc = {bv.x, bv.y, bv.z, bv.w};
#pragma unroll
    for (int ks = 0; ks < KS; ++ks)
      acc = __builtin_amdgcn_mfma_f32_16x16x32_bf16(
          __builtin_bit_cast(bf16x8, wf[mt][ks]), __builtin_bit_cast(bf16x8, bfrag[ks]),
          acc, 0, 0, 0);
    const int fb = mt * 16 + g * 4;
    u16x4 q;
    q[0] = f2bf(fmaxf(acc[0], 0.f));
    q[1] = f2bf(fmaxf(acc[1], 0.f));
    q[2] = f2bf(fmaxf(acc[2], 0.f));
    q[3] = f2bf(fmaxf(acc[3], 0.f));
    *(u16x4*)(dst + swz(edge, fb)) = q;
  }
}

// ---------------- main: gather + MLP + atomic scatter ----------------
__global__ __launch_bounds__(256, 2)
void gnn_main(const float* __restrict__ x, const int* __restrict__ ei,
              const float* __restrict__ ea, const unsigned short* __restrict__ wt,
              const float* __restrict__ b1, const float* __restrict__ b2,
              const float* __restrict__ b3, const float* __restrict__ b4,
              float* __restrict__ out, float* __restrict__ cnt, int E, int numTiles) {
  __shared__ __align__(16) unsigned char lds[4 * 8192 + 288 * 4];
  float* biasLds = (float*)(lds + 4 * 8192);
  for (int i = threadIdx.x; i < 288; i += 256) {
    float v;
    if (i < 64) v = b1[i];
    else if (i < 192) v = b2[i - 64];
    else if (i < 256) v = b3[i - 192];
    else v = b4[i - 256];
    biasLds[i] = v;
  }
  __syncthreads();

  const int lane = threadIdx.x & 63, wid = threadIdx.x >> 6;
  const int edge = lane & 15, g = lane >> 4;
  unsigned char* buf0 = lds + wid * 8192;
  unsigned char* buf1 = buf0 + 4096;

  // preload all weight fragments into registers (A-operand: row = lane&15, k contiguous 8)
  const unsigned short* w1t = wt;
  const unsigned short* w2t = wt + 4096;
  const unsigned short* w3t = wt + 12288;
  const unsigned short* w4t = wt + 20480;
  u16x8 wf1[4][2], wf2[8][2], wf3[4][4], wf4[2][2];
#pragma unroll
  for (int mt = 0; mt < 4; ++mt)
#pragma unroll
    for (int ks = 0; ks < 2; ++ks)
      wf1[mt][ks] = *(const u16x8*)(w1t + (mt * 16 + edge) * 64 + ks * 32 + g * 8);
#pragma unroll
  for (int mt = 0; mt < 8; ++mt)
#pragma unroll
    for (int ks = 0; ks < 2; ++ks)
      wf2[mt][ks] = *(const u16x8*)(w2t + (mt * 16 + edge) * 64 + ks * 32 + g * 8);
#pragma unroll
  for (int mt = 0; mt < 4; ++mt)
#pragma unroll
    for (int ks = 0; ks < 4; ++ks)
      wf3[mt][ks] = *(const u16x8*)(w3t + (mt * 16 + edge) * 128 + ks * 32 + g * 8);
#pragma unroll
  for (int mt = 0; mt < 2; ++mt)
#pragma unroll
    for (int ks = 0; ks < 2; ++ks)
      wf4[mt][ks] = *(const u16x8*)(w4t + (mt * 16 + edge) * 64 + ks * 32 + g * 8);

  const int wgl = blockIdx.x * 4 + wid;
  const int wstride = gridDim.x * 4;
  for (int tile = wgl; tile < numTiles; tile += wstride) {
    const int ebase = tile * 16;

    // ---- stage H0 = concat(x[dst], edge_attr) as bf16 [16][64] ----
    const int el = ebase + (lane >> 2);   // staging edge for this lane
    const int part = lane & 3;            // 8-feat slice
    float4 xa = {0,0,0,0}, xb = xa, ya = xa, yb = xa;
    if (el < E) {
      const int dn = ei[E + el];
      const float4* xp = (const float4*)(x + (size_t)dn * 32 + part * 8);
      xa = xp[0]; xb = xp[1];
      const float4* ep = (const float4*)(ea + (size_t)el * 32 + part * 8);
      ya = ep[0]; yb = ep[1];
    }
    u16x8 hx, he;
    hx[0]=f2bf(xa.x); hx[1]=f2bf(xa.y); hx[2]=f2bf(xa.z); hx[3]=f2bf(xa.w);
    hx[4]=f2bf(xb.x); hx[5]=f2bf(xb.y); hx[6]=f2bf(xb.z); hx[7]=f2bf(xb.w);
    he[0]=f2bf(ya.x); he[1]=f2bf(ya.y); he[2]=f2bf(ya.z); he[3]=f2bf(ya.w);
    he[4]=f2bf(yb.x); he[5]=f2bf(yb.y); he[6]=f2bf(yb.z); he[7]=f2bf(yb.w);
    const int e2 = lane >> 2;
    *(u16x8*)(buf0 + swz(e2, part * 8)) = hx;
    *(u16x8*)(buf0 + swz(e2, 32 + part * 8)) = he;

    const int eA = ebase + edge;                       // this lane's output edge
    const int dstA = (eA < E) ? ei[E + eA] : 0;

    mlp_layer<4, 2>(buf0, buf1, wf1, biasLds + 0,   lane);
    mlp_layer<8, 2>(buf1, buf0, wf2, biasLds + 64,  lane);
    mlp_layer<4, 4>(buf0, buf1, wf3, biasLds + 192, lane);

    // ---- layer 4 + atomic mean-scatter ----
    asm volatile("s_waitcnt lgkmcnt(0)" ::: "memory");
    u16x8 bf4[2];
#pragma unroll
    for (int ks = 0; ks < 2; ++ks)
      bf4[ks] = *(const u16x8*)(buf1 + swz(edge, ks * 32 + g * 8));
#pragma unroll
    for (int mt = 0; mt < 2; ++mt) {
      const float4 bv = *(const float4*)(biasLds + 256 + mt * 16 + g * 4);
      f32x4 acc = {bv.x, bv.y, bv.z, bv.w};
#pragma unroll
      for (int ks = 0; ks < 2; ++ks)
        acc = __builtin_amdgcn_mfma_f32_16x16x32_bf16(
            __builtin_bit_cast(bf16x8, wf4[mt][ks]), __builtin_bit_cast(bf16x8, bf4[ks]),
            acc, 0, 0, 0);
      if (eA < E) {
        float* op = out + (size_t)dstA * 32 + mt * 16 + g * 4;
#pragma unroll
        for (int r = 0; r < 4; ++r) unsafeAtomicAdd(op + r, fmaxf(acc[r], 0.f));
      }
    }
    if (lane < 16 && eA < E) unsafeAtomicAdd(cnt + dstA, 1.0f);
  }
}

__global__ void div_kernel(float* __restrict__ out, const float* __restrict__ cnt, int total) {
  int i = blockIdx.x * 256 + threadIdx.x;
  if (i < total) out[i] = out[i] / fmaxf(cnt[i >> 5], 1.0f);
}

extern "C" void kernel_launch(void* const* d_in, const int* in_sizes, int n_in,
                              void* d_out, int out_size, void* d_ws, size_t ws_size,
                              hipStream_t stream) {
  const float* x  = (const float*)d_in[0];
  const int*   ei = (const int*)d_in[1];
  const float* ea = (const float*)d_in[2];
  const float* W1 = (const float*)d_in[3];
  const float* b1 = (const float*)d_in[4];
  const float* W2 = (const float*)d_in[5];
  const float* b2 = (const float*)d_in[6];
  const float* W3 = (const float*)d_in[7];
  const float* b3 = (const float*)d_in[8];
  const float* W4 = (const float*)d_in[9];
  const float* b4 = (const float*)d_in[10];
  const int N = in_sizes[0] / 32;
  const int E = in_sizes[1] / 2;
  float* out = (float*)d_out;
  float* cnt = (float*)d_ws;
  unsigned short* wt = (unsigned short*)((char*)d_ws + (((size_t)N * 4 + 255) / 256) * 256);

  hipMemsetAsync(d_out, 0, (size_t)out_size * sizeof(float), stream);
  hipMemsetAsync(cnt, 0, (size_t)N * sizeof(float), stream);
  prep_weights<<<(22528 + 255) / 256, 256, 0, stream>>>(W1, W2, W3, W4, wt);
  const int numTiles = (E + 15) / 16;
  gnn_main<<<512, 256, 0, stream>>>(x, ei, ea, wt, b1, b2, b3, b4, out, cnt, E, numTiles);
  const int total = N * 32;
  div_kernel<<<(total + 255) / 256, 256, 0, stream>>>(out, cnt, total);
}